// Round 7
// baseline (4904.517 us; speedup 1.0000x reference)
//
#include <hip/hip_runtime.h>

#define T_STEPS 1000
#define DT 0.1f
#define HIDDEN 128
#define N_AGENTS 1024
#define UNROLL 8
#define RING (UNROLL + 31)   // 39 pending-accumulator slots

// tanh(x) = 1 - 2/(exp(2x)+1); exact at +/-inf, ~1e-7 rel error.
__device__ __forceinline__ float tanh_fast(float x) {
    float e = __expf(2.0f * x);
    return 1.0f - 2.0f * __builtin_amdgcn_rcpf(e + 1.0f);
}

// Opaque 16B load: asm results can't be remat'd/sunk, so the weights stay
// register-file-resident (R6 evidence: they land in AGPRs; gfx950 VALU
// reads AGPRs directly, so that's free).
__device__ __forceinline__ float4 opaque_load16(const float* p) {
    float4 v;
    asm volatile("global_load_dwordx4 %0, %1, off\n\ts_waitcnt vmcnt(0)"
                 : "=v"(v)
                 : "v"((unsigned long long)(uintptr_t)p)
                 : "memory");
    return v;
}

// PUSH-MODEL simulation. One agent per block of 128 threads (2 waves);
// lane tid owns W1 row tid (128 weight floats, opaque-loaded).
//
// R6 post-mortem: per-step LDS window reads were the bottleneck (16
// ds_read_b128 x 16 waves x ~12cyc = 3072 cyc/CU-step = measured 3000).
// Fix: h_pre(t) = sum_a W[a].e(t-a) accumulated FORWARD: when e(s) is
// produced (wave-uniform, computed redundantly by every lane), each lane
// pushes W[a]*e(s) into a register ring R[j] of pending h_pre values for
// iterations s..s+31. At step t, R[t-slot] is complete. Zero LDS history
// reads; ring indices compile-time via 8x unroll + rotate-by-8.
//
// Layer 2: q=W2[own_row]*h, qq=W2[other_row]*h; shfl_xor(1) folds qq so
// even lanes carry pairwise p0, odd lanes p1; 5 parity-preserving
// butterflies (2..32) give per-wave P0/P1; one float4 LDS exchange + one
// 2-wave barrier per step (parity double-buffered).
__global__ __launch_bounds__(128)
__attribute__((amdgpu_waves_per_eu(2, 2)))
void sim_kernel(const float* __restrict__ target_pos,
                const float* __restrict__ logsigma,
                const float* __restrict__ x_inits,
                const float* W1,
                const float* __restrict__ b1,
                const float* __restrict__ W2,
                const float* __restrict__ b2,
                float2* __restrict__ ws) {
    const int agent = blockIdx.x;
    const int tid  = threadIdx.x;   // 0..127 = W1/W2 row (hidden unit)
    const int wave = tid >> 6;      // 0 or 1
    const int lane = tid & 63;

    __shared__ alignas(16) float pbf[2][4];  // [parity][w0p0,w0p1,w1p0,w1p1]

    const float tx0 = target_pos[0], ty0 = target_pos[1];
    const float tx1 = target_pos[2], ty1 = target_pos[3];
    const float tx2 = target_pos[4], ty2 = target_pos[5];
    const float is0 = 1.0f / expf(logsigma[0]);
    const float is1 = 1.0f / expf(logsigma[1]);
    const float is2 = 1.0f / expf(logsigma[2]);

    // Full W1 row in registers via opaque loads.
    // Layout: W[3a]=x-weight(age a), W[3a+1]=y, W[3a+2]=th, W[96+a]=conc.
    float W[128];
    {
        const float* rowp = W1 + tid * 128;
        #pragma unroll
        for (int i = 0; i < 32; ++i) {
            float4 v = opaque_load16(rowp + 4 * i);
            W[4*i] = v.x; W[4*i+1] = v.y; W[4*i+2] = v.z; W[4*i+3] = v.w;
        }
    }

    const float b1r   = b1[tid];
    const float w2own = W2[(tid & 1) * HIDDEN + tid];
    const float w2oth = W2[((tid & 1) ^ 1) * HIDDEN + tid];
    const float b2x = b2[0], b2y = b2[1];

    float x  = x_inits[3 * agent];
    float y  = x_inits[3 * agent + 1];
    float th = x_inits[3 * agent + 2];

    auto conc = [&](float px, float py) {
        float dx0 = px - tx0, dy0 = py - ty0;
        float dx1 = px - tx1, dy1 = py - ty1;
        float dx2 = px - tx2, dy2 = py - ty2;
        float cc  = is0 * __expf(-(dx0*dx0 + dy0*dy0) * is0);
        cc       += is1 * __expf(-(dx1*dx1 + dy1*dy1) * is1);
        cc       += is2 * __expf(-(dx2*dx2 + dy2*dy2) * is2);
        return cc;
    };

    float c = conc(x, y);

    // Pending ring: R[j] = accumulated h_pre contribution to iteration
    // (current_base + j). Pre-seed the 31 virtual pushes of e(0) (history
    // pre-filled with the initial state): R[j] = sum_{a=j+1}^{31} contrib(a).
    float R[RING];
    #pragma unroll
    for (int j = 31; j < RING; ++j) R[j] = 0.f;
    {
        float acc = 0.f;
        #pragma unroll
        for (int a = 31; a >= 1; --a) {
            acc += W[3*a] * x + W[3*a+1] * y + W[3*a+2] * th + W[96+a] * c;
            R[a-1] = acc;
        }
    }

    float S_c = 0.f, S_u = 0.f;

    #pragma unroll 1
    for (int tt = 0; tt < T_STEPS / UNROLL; ++tt) {
        #pragma unroll
        for (int j = 0; j < UNROLL; ++j) {
            // ---- push e(t) into the pending ring: 128 FMAs ----
            #pragma unroll
            for (int a = 0; a < 32; ++a) {
                R[j+a] = fmaf(W[3*a], x,
                          fmaf(W[3*a+1], y,
                           fmaf(W[3*a+2], th,
                            fmaf(W[96+a], c, R[j+a]))));
            }
            // ---- layer 1 output for this iteration is now complete ----
            float h = fmaxf(R[j] + b1r, 0.f);

            // ---- layer 2: cross-multiply + parity butterfly (6 shfls) ----
            float q  = w2own * h;
            float qq = w2oth * h;
            float p  = q + __shfl_xor(qq, 1);
            #pragma unroll
            for (int off = 2; off <= 32; off <<= 1) p += __shfl_xor(p, off);
            // even lanes: wave-sum of W2[0]*h ; odd lanes: W2[1]*h
            if (lane < 2) pbf[j & 1][wave * 2 + lane] = p;
            __syncthreads();
            float4 pa = *(const float4*)pbf[j & 1];
            float P0 = pa.x + pa.z;
            float P1 = pa.y + pa.w;

            // ---- controls + dynamics (uniform on all lanes) ----
            float v  = tanh_fast(P0 + b2x);
            float wv = tanh_fast(P1 + b2y);
            S_u += v * v + wv * wv;

            float sn = __sinf(th), cs = __cosf(th);
            float dv = DT * v;
            x  = fmaf(dv, cs, x);
            y  = fmaf(dv, sn, y);
            th = fmaf(DT, wv, th);

            c = conc(x, y);
            S_c += c;
        }
        // ---- rotate pending ring by UNROLL ----
        #pragma unroll
        for (int j = 0; j < 31; ++j) R[j] = R[j + UNROLL];
        #pragma unroll
        for (int j = 31; j < RING; ++j) R[j] = 0.f;
    }

    if (tid == 0) ws[agent] = make_float2(S_c, S_u);
}

__global__ void reduce_kernel(const float2* __restrict__ ws,
                              float* __restrict__ out) {
    const int tid = threadIdx.x;  // 256 threads
    float sc = 0.f, su = 0.f;
    for (int i = tid; i < N_AGENTS; i += 256) {
        float2 v = ws[i];
        sc += v.x;
        su += v.y;
    }
    #pragma unroll
    for (int off = 32; off > 0; off >>= 1) {
        sc += __shfl_xor(sc, off);
        su += __shfl_xor(su, off);
    }
    __shared__ float2 partw[4];
    int wave = tid >> 6;
    if ((tid & 63) == 0) partw[wave] = make_float2(sc, su);
    __syncthreads();
    if (tid == 0) {
        float SC = partw[0].x + partw[1].x + partw[2].x + partw[3].x;
        float SU = partw[0].y + partw[1].y + partw[2].y + partw[3].y;
        const float invNT  = 1.0f / (float)(N_AGENTS * T_STEPS);
        const float invNT2 = 1.0f / (float)(N_AGENTS * T_STEPS * 2);
        out[0] = -SC * invNT + SU * invNT2;
    }
}

extern "C" void kernel_launch(void* const* d_in, const int* in_sizes, int n_in,
                              void* d_out, int out_size, void* d_ws, size_t ws_size,
                              hipStream_t stream) {
    const float* target_pos = (const float*)d_in[0];
    const float* logsigma   = (const float*)d_in[1];
    const float* x_inits    = (const float*)d_in[2];
    const float* W1         = (const float*)d_in[3];
    const float* b1         = (const float*)d_in[4];
    const float* W2         = (const float*)d_in[5];
    const float* b2         = (const float*)d_in[6];
    float2* ws = (float2*)d_ws;

    sim_kernel<<<N_AGENTS, 128, 0, stream>>>(target_pos, logsigma, x_inits,
                                             W1, b1, W2, b2, ws);
    reduce_kernel<<<1, 256, 0, stream>>>(ws, (float*)d_out);
}